// Round 8
// baseline (108.071 us; speedup 1.0000x reference)
//
#include <hip/hip_runtime.h>

#define B_SZ 8192
#define D_SZ 4096

// ws float layout (PC = row-chunks, 256 or 128 by ws_size):
//   part [8][PC][D] at 0          seg: 0=m_all 1=m_c1 2=l_all 3=l_c1 4=z_all 5=z_c1 6=q_all 7=q_c1
//   red  [4][8][D]  at 8*PC*D     four r-quarters of the PC-reduction
//   sc   [8]        after red     [0]=cnt1 [1]=ld_all [2]=ld_c1
//   dslots (dbl)    after sc      64 x {S0,S1,L0,L1}

__device__ __forceinline__ void acc4(float4& a, const float4 v) {
    a.x += v.x; a.y += v.y; a.z += v.z; a.w += v.w;
}
__device__ __forceinline__ void fma4(float4& a, const float4 v, const float k) {
    a.x = fmaf(v.x, k, a.x); a.y = fmaf(v.y, k, a.y);
    a.z = fmaf(v.z, k, a.z); a.w = fmaf(v.w, k, a.w);
}
__device__ __forceinline__ float4 sq4(const float4 v) {
    return {v.x * v.x, v.y * v.y, v.z * v.z, v.w * v.w};
}

// Stage 1: blocks [0, 4*PC) do interleaved 3-array masked column sums;
// block 4*PC computes the target-count/logdet scalars (consumed next kernel).
template <int PC>
__global__ __launch_bounds__(256, 4)
void stage1_kernel(const float* __restrict__ z,
                   const float* __restrict__ mean,
                   const float* __restrict__ lsd,
                   const int* __restrict__ target,
                   const float* __restrict__ logdet,
                   float* __restrict__ part,
                   float* __restrict__ sc) {
    constexpr int RP = B_SZ / PC;

    if (blockIdx.x == 4 * PC) {
        __shared__ float rsm[3][4];
        float c = 0.f, a = 0.f, o = 0.f;
#pragma unroll
        for (int k = 0; k < 8; ++k) {
            const int i = k * 1024 + (threadIdx.x << 2);
            const int4   t = *(const int4*)(target + i);
            const float4 l = *(const float4*)(logdet + i);
            const float n0 = (t.x == 1) ? 1.f : 0.f;
            const float n1 = (t.y == 1) ? 1.f : 0.f;
            const float n2 = (t.z == 1) ? 1.f : 0.f;
            const float n3 = (t.w == 1) ? 1.f : 0.f;
            c += n0 + n1 + n2 + n3;                   // exact: integer-valued
            a += l.x + l.y + l.z + l.w;
            o += l.x * n0 + l.y * n1 + l.z * n2 + l.w * n3;
        }
        for (int off = 32; off > 0; off >>= 1) {
            c += __shfl_down(c, off);
            a += __shfl_down(a, off);
            o += __shfl_down(o, off);
        }
        const int w = threadIdx.x >> 6;
        if ((threadIdx.x & 63) == 0) { rsm[0][w] = c; rsm[1][w] = a; rsm[2][w] = o; }
        __syncthreads();
        if (threadIdx.x == 0) {
            sc[0] = rsm[0][0] + rsm[0][1] + rsm[0][2] + rsm[0][3];
            sc[1] = rsm[1][0] + rsm[1][1] + rsm[1][2] + rsm[1][3];
            sc[2] = rsm[2][0] + rsm[2][1] + rsm[2][2] + rsm[2][3];
        }
        return;
    }

    const int col = (blockIdx.x & 3) * 1024 + (threadIdx.x << 2);
    const int r   = blockIdx.x >> 2;
    const size_t base0 = (size_t)(r * RP) * D_SZ + col;

    const float* pz = z    + base0;
    const float* pm = mean + base0;
    const float* pl = lsd  + base0;
    const int*   pt = target + r * RP;

    float4 mA = {0,0,0,0}, m1 = {0,0,0,0};
    float4 lA = {0,0,0,0}, l1 = {0,0,0,0};
    float4 zA = {0,0,0,0}, z1 = {0,0,0,0};
    float4 qA = {0,0,0,0}, q1 = {0,0,0,0};

    for (int it = 0; it < RP / 4; ++it) {
        const float4 vz0 = *(const float4*)(pz);
        const float4 vz1 = *(const float4*)(pz + 1 * D_SZ);
        const float4 vz2 = *(const float4*)(pz + 2 * D_SZ);
        const float4 vz3 = *(const float4*)(pz + 3 * D_SZ);
        const float4 vm0 = *(const float4*)(pm);
        const float4 vm1 = *(const float4*)(pm + 1 * D_SZ);
        const float4 vm2 = *(const float4*)(pm + 2 * D_SZ);
        const float4 vm3 = *(const float4*)(pm + 3 * D_SZ);
        const float4 vl0 = *(const float4*)(pl);
        const float4 vl1 = *(const float4*)(pl + 1 * D_SZ);
        const float4 vl2 = *(const float4*)(pl + 2 * D_SZ);
        const float4 vl3 = *(const float4*)(pl + 3 * D_SZ);
        const int4   t   = *(const int4*)(pt);
        __builtin_amdgcn_sched_barrier(0);

        const float k0 = (t.x == 1) ? 1.f : 0.f;
        const float k1 = (t.y == 1) ? 1.f : 0.f;
        const float k2 = (t.z == 1) ? 1.f : 0.f;
        const float k3 = (t.w == 1) ? 1.f : 0.f;

        acc4(mA, vm0); fma4(m1, vm0, k0);
        acc4(mA, vm1); fma4(m1, vm1, k1);
        acc4(mA, vm2); fma4(m1, vm2, k2);
        acc4(mA, vm3); fma4(m1, vm3, k3);

        acc4(lA, vl0); fma4(l1, vl0, k0);
        acc4(lA, vl1); fma4(l1, vl1, k1);
        acc4(lA, vl2); fma4(l1, vl2, k2);
        acc4(lA, vl3); fma4(l1, vl3, k3);

        acc4(zA, vz0); fma4(z1, vz0, k0);
        acc4(zA, vz1); fma4(z1, vz1, k1);
        acc4(zA, vz2); fma4(z1, vz2, k2);
        acc4(zA, vz3); fma4(z1, vz3, k3);

        const float4 q0  = sq4(vz0); acc4(qA, q0);  fma4(q1, q0,  k0);
        const float4 qq1 = sq4(vz1); acc4(qA, qq1); fma4(q1, qq1, k1);
        const float4 q2  = sq4(vz2); acc4(qA, q2);  fma4(q1, q2,  k2);
        const float4 q3  = sq4(vz3); acc4(qA, q3);  fma4(q1, q3,  k3);

        pz += 4 * D_SZ; pm += 4 * D_SZ; pl += 4 * D_SZ; pt += 4;
    }

    *(float4*)(part + ((size_t)(0 * PC + r)) * D_SZ + col) = mA;
    *(float4*)(part + ((size_t)(1 * PC + r)) * D_SZ + col) = m1;
    *(float4*)(part + ((size_t)(2 * PC + r)) * D_SZ + col) = lA;
    *(float4*)(part + ((size_t)(3 * PC + r)) * D_SZ + col) = l1;
    *(float4*)(part + ((size_t)(4 * PC + r)) * D_SZ + col) = zA;
    *(float4*)(part + ((size_t)(5 * PC + r)) * D_SZ + col) = z1;
    *(float4*)(part + ((size_t)(6 * PC + r)) * D_SZ + col) = qA;
    *(float4*)(part + ((size_t)(7 * PC + r)) * D_SZ + col) = q1;
}

// Stage 2: reduce partials. 128 blocks = 8 segs x 4 col-chunks x 4 r-quarters.
__global__ __launch_bounds__(256)
void reduce_kernel(const float* __restrict__ part,
                   float* __restrict__ red, int PC_) {
    const int seg = blockIdx.x >> 4;
    const int rem = blockIdx.x & 15;
    const int col = (rem >> 2) * 1024 + (threadIdx.x << 2);
    const int q   = rem & 3;
    const int rq  = PC_ >> 2;
    float4 acc = {0,0,0,0};
    for (int r = q * rq; r < (q + 1) * rq; ++r) {
        const float4 v = *(const float4*)(part + ((size_t)seg * PC_ + r) * D_SZ + col);
        acc4(acc, v);
    }
    *(float4*)(red + ((size_t)(q * 8 + seg)) * D_SZ + col) = acc;
}

// Per column d: combine quarters, write mu/lsd outputs, per-wave double partials.
__global__ __launch_bounds__(256)
void finalize_cols_kernel(const float* __restrict__ red,
                          const float* __restrict__ sc,
                          double* __restrict__ dslots,
                          float* __restrict__ out) {
    const int d = blockIdx.x * 256 + threadIdx.x;
    const float cnt1 = sc[0];
    const float cnt0 = (float)B_SZ - cnt1;

#define RSEG(s) (red[(0 * 8 + (s)) * D_SZ + d] + red[(1 * 8 + (s)) * D_SZ + d] + \
                 red[(2 * 8 + (s)) * D_SZ + d] + red[(3 * 8 + (s)) * D_SZ + d])
    const float ma = RSEG(0), m1 = RSEG(1);
    const float la = RSEG(2), l1 = RSEG(3);
    const float za = RSEG(4), z1 = RSEG(5);
    const float qa = RSEG(6), q1 = RSEG(7);
#undef RSEG

    const float mu1 = m1 / cnt1, mu0 = (ma - m1) / cnt0;
    const float ls1 = l1 / cnt1, ls0 = (la - l1) / cnt0;

    // outputs: [0]=prior, [1,1+2D)=mus (class-major), [1+2D,1+4D)=lsds, [1+4D..]=lp
    out[1 + d]            = mu0;
    out[1 + D_SZ + d]     = mu1;
    out[1 + 2 * D_SZ + d] = ls0;
    out[1 + 3 * D_SZ + d] = ls1;

    const float z0 = za - z1, q0 = qa - q1;
    const double w0 = 0.5 * exp(-2.0 * (double)ls0);
    const double w1 = 0.5 * exp(-2.0 * (double)ls1);
    // sum_{i in c} (z - mu)^2 = Q_c - 2 mu_c Z_c + cnt_c mu_c^2
    double S0 = w0 * ((double)q0 - 2.0 * (double)mu0 * (double)z0 + (double)cnt0 * (double)mu0 * (double)mu0);
    double S1 = w1 * ((double)q1 - 2.0 * (double)mu1 * (double)z1 + (double)cnt1 * (double)mu1 * (double)mu1);
    double L0 = (double)ls0;
    double L1 = (double)ls1;

    for (int off = 32; off > 0; off >>= 1) {
        S0 += __shfl_down(S0, off);
        S1 += __shfl_down(S1, off);
        L0 += __shfl_down(L0, off);
        L1 += __shfl_down(L1, off);
    }
    if ((threadIdx.x & 63) == 0) {
        double* wd = dslots + (blockIdx.x * 4 + (threadIdx.x >> 6)) * 4;
        wd[0] = S0; wd[1] = S1; wd[2] = L0; wd[3] = L1;
    }
}

// One wave sums the 64 dslots, emits scalar outputs.
__global__ void finalize_scalars_kernel(const float* __restrict__ sc,
                                        const double* __restrict__ dslots,
                                        float* __restrict__ out) {
    const double* p = dslots + threadIdx.x * 4;
    double S0 = p[0], S1 = p[1], L0 = p[2], L1 = p[3];
    for (int off = 32; off > 0; off >>= 1) {
        S0 += __shfl_down(S0, off);
        S1 += __shfl_down(S1, off);
        L0 += __shfl_down(L0, off);
        L1 += __shfl_down(L1, off);
    }
    if (threadIdx.x == 0) {
        const double LOG2PI = 1.8378770664093453;
        const double cnt1 = (double)sc[0];
        const double cnt0 = (double)B_SZ - cnt1;
        const double ldm1 = (double)sc[2] / cnt1;
        const double ldm0 = ((double)sc[1] - (double)sc[2]) / cnt0;

        const double c0 = -0.5 * LOG2PI * (double)D_SZ - L0;
        const double c1 = -0.5 * LOG2PI * (double)D_SZ - L1;
        const double lp0 = c0 - S0 / cnt0;
        const double lp1 = c1 - S1 / cnt1;

        out[1 + 4 * D_SZ + 0] = (float)lp0;
        out[1 + 4 * D_SZ + 1] = (float)lp1;
        out[0] = (float)(0.5 * ((lp0 + ldm0) + (lp1 + ldm1)));
    }
}

extern "C" void kernel_launch(void* const* d_in, const int* in_sizes, int n_in,
                              void* d_out, int out_size, void* d_ws, size_t ws_size,
                              hipStream_t stream) {
    const float* z      = (const float*)d_in[0];
    const float* mean   = (const float*)d_in[1];
    const float* log_sd = (const float*)d_in[2];
    const int*   target = (const int*)d_in[3];
    const float* logdet = (const float*)d_in[4];
    float* out = (float*)d_out;
    float* ws  = (float*)d_ws;

    // PC=256 if the partial buffer fits, else 128 (R7-verified footprint).
    const size_t need256 = ((size_t)256 * 8 * D_SZ + 32 * D_SZ + 8) * 4 + 64 * 4 * 8;
    const int PC = (ws_size >= need256) ? 256 : 128;

    float*  part   = ws;
    float*  red    = ws + (size_t)PC * 8 * D_SZ;
    float*  sc     = red + 32 * D_SZ;
    double* dslots = (double*)(sc + 8);

    if (PC == 256) {
        stage1_kernel<256><<<4 * 256 + 1, 256, 0, stream>>>(z, mean, log_sd, target, logdet, part, sc);
    } else {
        stage1_kernel<128><<<4 * 128 + 1, 256, 0, stream>>>(z, mean, log_sd, target, logdet, part, sc);
    }
    reduce_kernel<<<128, 256, 0, stream>>>(part, red, PC);
    finalize_cols_kernel<<<D_SZ / 256, 256, 0, stream>>>(red, sc, dslots, out);
    finalize_scalars_kernel<<<1, 64, 0, stream>>>(sc, dslots, out);
}

// Round 9
// 86.914 us; speedup vs baseline: 1.2434x; 1.2434x over previous
//
#include <hip/hip_runtime.h>

#define B_SZ 8192
#define D_SZ 4096
#define PC   128            // row-chunks
#define RP   (B_SZ / PC)    // rows per chunk = 64

typedef float f32x4 __attribute__((ext_vector_type(4)));
typedef int   i32x4 __attribute__((ext_vector_type(4)));

// ws float layout:
//   part [8][PC][D] at 0        seg: 0=m_all 1=m_c1 2=l_all 3=l_c1 4=z_all 5=z_c1 6=q_all 7=q_c1
//   red  [2][8][D]  at 8*PC*D   two r-halves of the PC-reduction
//   sc   [8]        after red   [0]=cnt1 [1]=ld_all [2]=ld_c1
//   dslots (dbl)    after sc    64 x {S0,S1,L0,L1}

// Stage 1: blocks [0, 4*PC) interleaved 3-array masked column sums with
// asm-pinned 13-load batches; block 4*PC computes count/logdet scalars.
__global__ __launch_bounds__(256, 4)
void stage1_kernel(const float* __restrict__ z,
                   const float* __restrict__ mean,
                   const float* __restrict__ lsd,
                   const int* __restrict__ target,
                   const float* __restrict__ logdet,
                   float* __restrict__ part,
                   float* __restrict__ sc) {
    if (blockIdx.x == 4 * PC) {
        __shared__ float rsm[3][4];
        float c = 0.f, a = 0.f, o = 0.f;
#pragma unroll
        for (int k = 0; k < 8; ++k) {
            const int i = k * 1024 + (threadIdx.x << 2);
            const i32x4 t = *(const i32x4*)(target + i);
            const f32x4 l = *(const f32x4*)(logdet + i);
            const float n0 = (t.x == 1) ? 1.f : 0.f;
            const float n1 = (t.y == 1) ? 1.f : 0.f;
            const float n2 = (t.z == 1) ? 1.f : 0.f;
            const float n3 = (t.w == 1) ? 1.f : 0.f;
            c += n0 + n1 + n2 + n3;                   // exact: integer-valued
            a += l.x + l.y + l.z + l.w;
            o += l.x * n0 + l.y * n1 + l.z * n2 + l.w * n3;
        }
        for (int off = 32; off > 0; off >>= 1) {
            c += __shfl_down(c, off);
            a += __shfl_down(a, off);
            o += __shfl_down(o, off);
        }
        const int w = threadIdx.x >> 6;
        if ((threadIdx.x & 63) == 0) { rsm[0][w] = c; rsm[1][w] = a; rsm[2][w] = o; }
        __syncthreads();
        if (threadIdx.x == 0) {
            sc[0] = rsm[0][0] + rsm[0][1] + rsm[0][2] + rsm[0][3];
            sc[1] = rsm[1][0] + rsm[1][1] + rsm[1][2] + rsm[1][3];
            sc[2] = rsm[2][0] + rsm[2][1] + rsm[2][2] + rsm[2][3];
        }
        return;
    }

    const int col = (blockIdx.x & 3) * 1024 + (threadIdx.x << 2);
    const int r   = blockIdx.x >> 2;
    const size_t base0 = (size_t)(r * RP) * D_SZ + col;

    const float* pz = z    + base0;
    const float* pm = mean + base0;
    const float* pl = lsd  + base0;
    const int*   pt = target + r * RP;

    f32x4 mA = 0, m1 = 0, lA = 0, l1 = 0;
    f32x4 zA = 0, z1 = 0, qA = 0, q1 = 0;

#pragma unroll 1
    for (int it = 0; it < RP / 4; ++it) {
        // 13 loads into distinct registers...
        f32x4 vz0 = *(const f32x4*)(pz);
        f32x4 vz1 = *(const f32x4*)(pz + 1 * D_SZ);
        f32x4 vz2 = *(const f32x4*)(pz + 2 * D_SZ);
        f32x4 vz3 = *(const f32x4*)(pz + 3 * D_SZ);
        f32x4 vm0 = *(const f32x4*)(pm);
        f32x4 vm1 = *(const f32x4*)(pm + 1 * D_SZ);
        f32x4 vm2 = *(const f32x4*)(pm + 2 * D_SZ);
        f32x4 vm3 = *(const f32x4*)(pm + 3 * D_SZ);
        f32x4 vl0 = *(const f32x4*)(pl);
        f32x4 vl1 = *(const f32x4*)(pl + 1 * D_SZ);
        f32x4 vl2 = *(const f32x4*)(pl + 2 * D_SZ);
        f32x4 vl3 = *(const f32x4*)(pl + 3 * D_SZ);
        i32x4 t   = *(const i32x4*)(pt);
        // ...all forced complete & simultaneously live here (13 in flight):
        asm volatile("" : "+v"(vz0), "+v"(vz1), "+v"(vz2), "+v"(vz3),
                          "+v"(vm0), "+v"(vm1), "+v"(vm2), "+v"(vm3),
                          "+v"(vl0), "+v"(vl1), "+v"(vl2), "+v"(vl3),
                          "+v"(t));

        const float k0 = (t.x == 1) ? 1.f : 0.f;
        const float k1 = (t.y == 1) ? 1.f : 0.f;
        const float k2 = (t.z == 1) ? 1.f : 0.f;
        const float k3 = (t.w == 1) ? 1.f : 0.f;

        mA += vm0; m1 += vm0 * k0;
        mA += vm1; m1 += vm1 * k1;
        mA += vm2; m1 += vm2 * k2;
        mA += vm3; m1 += vm3 * k3;

        lA += vl0; l1 += vl0 * k0;
        lA += vl1; l1 += vl1 * k1;
        lA += vl2; l1 += vl2 * k2;
        lA += vl3; l1 += vl3 * k3;

        zA += vz0; z1 += vz0 * k0;
        zA += vz1; z1 += vz1 * k1;
        zA += vz2; z1 += vz2 * k2;
        zA += vz3; z1 += vz3 * k3;

        const f32x4 q0 = vz0 * vz0; qA += q0; q1 += q0 * k0;
        const f32x4 qb = vz1 * vz1; qA += qb; q1 += qb * k1;
        const f32x4 qc = vz2 * vz2; qA += qc; q1 += qc * k2;
        const f32x4 qd = vz3 * vz3; qA += qd; q1 += qd * k3;

        pz += 4 * D_SZ; pm += 4 * D_SZ; pl += 4 * D_SZ; pt += 4;
    }

    *(f32x4*)(part + ((size_t)(0 * PC + r)) * D_SZ + col) = mA;
    *(f32x4*)(part + ((size_t)(1 * PC + r)) * D_SZ + col) = m1;
    *(f32x4*)(part + ((size_t)(2 * PC + r)) * D_SZ + col) = lA;
    *(f32x4*)(part + ((size_t)(3 * PC + r)) * D_SZ + col) = l1;
    *(f32x4*)(part + ((size_t)(4 * PC + r)) * D_SZ + col) = zA;
    *(f32x4*)(part + ((size_t)(5 * PC + r)) * D_SZ + col) = z1;
    *(f32x4*)(part + ((size_t)(6 * PC + r)) * D_SZ + col) = qA;
    *(f32x4*)(part + ((size_t)(7 * PC + r)) * D_SZ + col) = q1;
}

// Stage 2: reduce partials. 64 blocks = 8 segs x 4 col-chunks x 2 r-halves.
__global__ __launch_bounds__(256)
void reduce_kernel(const float* __restrict__ part,
                   float* __restrict__ red) {
    const int seg  = blockIdx.x >> 3;
    const int rem  = blockIdx.x & 7;
    const int col  = (rem >> 1) * 1024 + (threadIdx.x << 2);
    const int half = rem & 1;
    f32x4 acc = 0;
    for (int r = half * (PC / 2); r < (half + 1) * (PC / 2); ++r) {
        acc += *(const f32x4*)(part + ((size_t)seg * PC + r) * D_SZ + col);
    }
    *(f32x4*)(red + ((size_t)(half * 8 + seg)) * D_SZ + col) = acc;
}

// Per column d: combine halves, write mu/lsd outputs, per-wave double partials.
__global__ __launch_bounds__(256)
void finalize_cols_kernel(const float* __restrict__ red,
                          const float* __restrict__ sc,
                          double* __restrict__ dslots,
                          float* __restrict__ out) {
    const int d = blockIdx.x * 256 + threadIdx.x;
    const float cnt1 = sc[0];
    const float cnt0 = (float)B_SZ - cnt1;

#define RSEG(s) (red[(s) * D_SZ + d] + red[(8 + (s)) * D_SZ + d])
    const float ma = RSEG(0), m1 = RSEG(1);
    const float la = RSEG(2), l1 = RSEG(3);
    const float za = RSEG(4), z1 = RSEG(5);
    const float qa = RSEG(6), q1 = RSEG(7);
#undef RSEG

    const float mu1 = m1 / cnt1, mu0 = (ma - m1) / cnt0;
    const float ls1 = l1 / cnt1, ls0 = (la - l1) / cnt0;

    // outputs: [0]=prior, [1,1+2D)=mus (class-major), [1+2D,1+4D)=lsds, [1+4D..]=lp
    out[1 + d]            = mu0;
    out[1 + D_SZ + d]     = mu1;
    out[1 + 2 * D_SZ + d] = ls0;
    out[1 + 3 * D_SZ + d] = ls1;

    const float z0 = za - z1, q0 = qa - q1;
    const double w0 = 0.5 * exp(-2.0 * (double)ls0);
    const double w1 = 0.5 * exp(-2.0 * (double)ls1);
    // sum_{i in c} (z - mu)^2 = Q_c - 2 mu_c Z_c + cnt_c mu_c^2
    double S0 = w0 * ((double)q0 - 2.0 * (double)mu0 * (double)z0 + (double)cnt0 * (double)mu0 * (double)mu0);
    double S1 = w1 * ((double)q1 - 2.0 * (double)mu1 * (double)z1 + (double)cnt1 * (double)mu1 * (double)mu1);
    double L0 = (double)ls0;
    double L1 = (double)ls1;

    for (int off = 32; off > 0; off >>= 1) {
        S0 += __shfl_down(S0, off);
        S1 += __shfl_down(S1, off);
        L0 += __shfl_down(L0, off);
        L1 += __shfl_down(L1, off);
    }
    if ((threadIdx.x & 63) == 0) {
        double* wd = dslots + (blockIdx.x * 4 + (threadIdx.x >> 6)) * 4;
        wd[0] = S0; wd[1] = S1; wd[2] = L0; wd[3] = L1;
    }
}

// One wave sums the 64 dslots, emits scalar outputs.
__global__ void finalize_scalars_kernel(const float* __restrict__ sc,
                                        const double* __restrict__ dslots,
                                        float* __restrict__ out) {
    const double* p = dslots + threadIdx.x * 4;
    double S0 = p[0], S1 = p[1], L0 = p[2], L1 = p[3];
    for (int off = 32; off > 0; off >>= 1) {
        S0 += __shfl_down(S0, off);
        S1 += __shfl_down(S1, off);
        L0 += __shfl_down(L0, off);
        L1 += __shfl_down(L1, off);
    }
    if (threadIdx.x == 0) {
        const double LOG2PI = 1.8378770664093453;
        const double cnt1 = (double)sc[0];
        const double cnt0 = (double)B_SZ - cnt1;
        const double ldm1 = (double)sc[2] / cnt1;
        const double ldm0 = ((double)sc[1] - (double)sc[2]) / cnt0;

        const double c0 = -0.5 * LOG2PI * (double)D_SZ - L0;
        const double c1 = -0.5 * LOG2PI * (double)D_SZ - L1;
        const double lp0 = c0 - S0 / cnt0;
        const double lp1 = c1 - S1 / cnt1;

        out[1 + 4 * D_SZ + 0] = (float)lp0;
        out[1 + 4 * D_SZ + 1] = (float)lp1;
        out[0] = (float)(0.5 * ((lp0 + ldm0) + (lp1 + ldm1)));
    }
}

extern "C" void kernel_launch(void* const* d_in, const int* in_sizes, int n_in,
                              void* d_out, int out_size, void* d_ws, size_t ws_size,
                              hipStream_t stream) {
    const float* z      = (const float*)d_in[0];
    const float* mean   = (const float*)d_in[1];
    const float* log_sd = (const float*)d_in[2];
    const int*   target = (const int*)d_in[3];
    const float* logdet = (const float*)d_in[4];
    float* out = (float*)d_out;
    float* ws  = (float*)d_ws;

    float*  part   = ws;
    float*  red    = ws + (size_t)PC * 8 * D_SZ;
    float*  sc     = red + 16 * D_SZ;
    double* dslots = (double*)(sc + 8);

    stage1_kernel<<<4 * PC + 1, 256, 0, stream>>>(z, mean, log_sd, target, logdet, part, sc);
    reduce_kernel<<<64, 256, 0, stream>>>(part, red);
    finalize_cols_kernel<<<D_SZ / 256, 256, 0, stream>>>(red, sc, dslots, out);
    finalize_scalars_kernel<<<1, 64, 0, stream>>>(sc, dslots, out);
}